// Round 3
// baseline (480.313 us; speedup 1.0000x reference)
//
#include <hip/hip_runtime.h>

#define HDIM 96

__global__ void zero_k(int* __restrict__ p, int n) {
  int i = blockIdx.x * blockDim.x + threadIdx.x;
  if (i < n) p[i] = 0;
}

// count in-degree AND record each edge's arrival rank at its dst
__global__ void deg_rank_k(const int* __restrict__ dst, int* __restrict__ indeg,
                           int* __restrict__ rank, int e) {
  int i = blockIdx.x * blockDim.x + threadIdx.x;
  if (i < e) rank[i] = atomicAdd(&indeg[dst[i]], 1);
}

// Single-block exclusive scan of indeg -> offsets[0..n]; also dis = rsqrt(1+indeg).
__global__ __launch_bounds__(1024) void scan_dis_k(const int* __restrict__ indeg,
                                                   int* __restrict__ offsets,
                                                   float* __restrict__ dis, int n) {
  __shared__ int wsum[16];
  __shared__ int carry_s;
  const int tid = threadIdx.x;
  const int lane = tid & 63, w = tid >> 6;
  if (tid == 0) carry_s = 0;
  __syncthreads();
  for (int base = 0; base < n; base += 1024) {
    const int i = base + tid;
    const int v = (i < n) ? indeg[i] : 0;
    int incl = v;
#pragma unroll
    for (int off = 1; off < 64; off <<= 1) {
      int t = __shfl_up(incl, off, 64);
      if (lane >= off) incl += t;
    }
    if (lane == 63) wsum[w] = incl;
    __syncthreads();
    if (tid < 16) {
      int s = wsum[tid];
#pragma unroll
      for (int off = 1; off < 16; off <<= 1) {
        int t = __shfl_up(s, off, 16);
        if (tid >= off) s += t;
      }
      wsum[tid] = s;
    }
    __syncthreads();
    const int carry = carry_s;
    incl += (w > 0 ? wsum[w - 1] : 0);
    if (i < n) {
      offsets[i] = carry + incl - v;
      dis[i] = rsqrtf((float)(1 + v));
    }
    __syncthreads();
    if (tid == 1023) carry_s = carry + incl;
    __syncthreads();
  }
  if (tid == 0) offsets[n] = carry_s;
}

// atomic-free slot calc; fire-and-forget atomicExch avoids partial-line store amplification
__global__ void place_k(const int* __restrict__ src, const int* __restrict__ dst,
                        const int* __restrict__ rank, const int* __restrict__ offsets,
                        int* __restrict__ csr_src, int e) {
  int i = blockIdx.x * blockDim.x + threadIdx.x;
  if (i >= e) return;
  int d = dst[i];
  atomicExch(&csr_src[offsets[d] + rank[i]], src[i]);
}

// agg[d,:] = dis[d] * ( dis[d]*h[d,:] + sum_{s->d} dis[s]*h[s,:] )
__global__ __launch_bounds__(192) void gather_k(
    const int* __restrict__ csr_src, const int* __restrict__ offsets,
    const float* __restrict__ dis, const float* __restrict__ h,
    float* __restrict__ agg, int n) {
  const int tid  = threadIdx.x;
  const int node = blockIdx.x * 8 + tid / 24;
  const int q    = tid % 24;
  if (node >= n) return;
  const float dd = dis[node];
  float4 acc = ((const float4*)(h + (size_t)node * HDIM))[q];
  acc.x *= dd; acc.y *= dd; acc.z *= dd; acc.w *= dd;
  int i = offsets[node];
  const int end = offsets[node + 1];
  for (; i + 1 < end; i += 2) {
    const int s0 = csr_src[i], s1 = csr_src[i + 1];
    const float w0 = dis[s0], w1 = dis[s1];
    const float4 v0 = ((const float4*)(h + (size_t)s0 * HDIM))[q];
    const float4 v1 = ((const float4*)(h + (size_t)s1 * HDIM))[q];
    acc.x = fmaf(w0, v0.x, acc.x); acc.y = fmaf(w0, v0.y, acc.y);
    acc.z = fmaf(w0, v0.z, acc.z); acc.w = fmaf(w0, v0.w, acc.w);
    acc.x = fmaf(w1, v1.x, acc.x); acc.y = fmaf(w1, v1.y, acc.y);
    acc.z = fmaf(w1, v1.z, acc.z); acc.w = fmaf(w1, v1.w, acc.w);
  }
  if (i < end) {
    const int s0 = csr_src[i];
    const float w0 = dis[s0];
    const float4 v0 = ((const float4*)(h + (size_t)s0 * HDIM))[q];
    acc.x = fmaf(w0, v0.x, acc.x); acc.y = fmaf(w0, v0.y, acc.y);
    acc.z = fmaf(w0, v0.z, acc.z); acc.w = fmaf(w0, v0.w, acc.w);
  }
  acc.x *= dd; acc.y *= dd; acc.z *= dd; acc.w *= dd;
  ((float4*)(agg + (size_t)node * HDIM))[q] = acc;
}

// ---- row-per-lane GEMM family ----
// One 64-row tile per block; block=128 (2 waves), wave w computes cols [48w, 48w+48).
// x-tile staged TRANSPOSED (stride 65) -> 1 ds_read_b32 per k.
// W/bias read via wave-uniform addresses -> scalar loads on the K$ pipe.

__device__ __forceinline__ void stage_tileT(const float* __restrict__ A, float* xsT,
                                            int row0, int n, int tid, int kofs) {
  for (int idx = tid; idx < 64 * 24; idx += 128) {
    int r = idx / 24, q = idx % 24;
    if (row0 + r < n) {
      float4 v = *(const float4*)(A + (size_t)(row0 + r) * HDIM + 4 * q);
      xsT[(kofs + 4 * q + 0) * 65 + r] = v.x;
      xsT[(kofs + 4 * q + 1) * 65 + r] = v.y;
      xsT[(kofs + 4 * q + 2) * 65 + r] = v.z;
      xsT[(kofs + 4 * q + 3) * 65 + r] = v.w;
    }
  }
}

template<bool RELU, bool DUAL>
__global__ __launch_bounds__(128) void gemm_row_k(
    const float* __restrict__ A,
    const float* __restrict__ W0, const float* __restrict__ b0, float* __restrict__ o0,
    const float* __restrict__ W1, const float* __restrict__ b1, float* __restrict__ o1,
    int n) {
  __shared__ float xsT[HDIM * 65];
  const int tid = threadIdx.x;
  const int lane = tid & 63;
  const int row0 = blockIdx.x * 64;
  stage_tileT(A, xsT, row0, n, tid, 0);
  __syncthreads();
  const int cbase = __builtin_amdgcn_readfirstlane((tid >> 6) * 48);
  const bool live = (row0 + lane < n);
#pragma unroll
  for (int m = 0; m < (DUAL ? 2 : 1); m++) {
    const float* W = m ? W1 : W0;
    const float* bias = m ? b1 : b0;
    float* out = m ? o1 : o0;
    float acc[48];
#pragma unroll
    for (int c = 0; c < 48; c += 4) {
      float4 b = *(const float4*)(bias + cbase + c);
      acc[c] = b.x; acc[c+1] = b.y; acc[c+2] = b.z; acc[c+3] = b.w;
    }
    for (int k = 0; k < HDIM; k++) {
      const float xk = xsT[k * 65 + lane];
      const float* wrow = W + k * HDIM + cbase;
#pragma unroll
      for (int c = 0; c < 48; c += 4) {
        float4 wv = *(const float4*)(wrow + c);
        acc[c]   = fmaf(xk, wv.x, acc[c]);
        acc[c+1] = fmaf(xk, wv.y, acc[c+1]);
        acc[c+2] = fmaf(xk, wv.z, acc[c+2]);
        acc[c+3] = fmaf(xk, wv.w, acc[c+3]);
      }
    }
    if (live) {
      float* orow = out + (size_t)(row0 + lane) * HDIM + cbase;
#pragma unroll
      for (int c = 0; c < 48; c += 4) {
        float4 o;
        o.x = acc[c]; o.y = acc[c+1]; o.z = acc[c+2]; o.w = acc[c+3];
        if (RELU) {
          o.x = fmaxf(o.x, 0.f); o.y = fmaxf(o.y, 0.f);
          o.z = fmaxf(o.z, 0.f); o.w = fmaxf(o.w, 0.f);
        }
        *(float4*)(orow + c) = o;
      }
    }
  }
}

// out[n,96] = A0[n,96] @ W[0:96,:] + A1[n,96] @ W[96:192,:] + bias   (K=192)
__global__ __launch_bounds__(128) void gemm_concat_k(
    const float* __restrict__ A0, const float* __restrict__ A1,
    const float* __restrict__ W, const float* __restrict__ bias,
    float* __restrict__ out, int n) {
  __shared__ float xsT[192 * 65];
  const int tid = threadIdx.x;
  const int lane = tid & 63;
  const int row0 = blockIdx.x * 64;
  stage_tileT(A0, xsT, row0, n, tid, 0);
  stage_tileT(A1, xsT, row0, n, tid, HDIM);
  __syncthreads();
  const int cbase = __builtin_amdgcn_readfirstlane((tid >> 6) * 48);
  float acc[48];
#pragma unroll
  for (int c = 0; c < 48; c += 4) {
    float4 b = *(const float4*)(bias + cbase + c);
    acc[c] = b.x; acc[c+1] = b.y; acc[c+2] = b.z; acc[c+3] = b.w;
  }
  for (int k = 0; k < 192; k++) {
    const float xk = xsT[k * 65 + lane];
    const float* wrow = W + k * HDIM + cbase;
#pragma unroll
    for (int c = 0; c < 48; c += 4) {
      float4 wv = *(const float4*)(wrow + c);
      acc[c]   = fmaf(xk, wv.x, acc[c]);
      acc[c+1] = fmaf(xk, wv.y, acc[c+1]);
      acc[c+2] = fmaf(xk, wv.z, acc[c+2]);
      acc[c+3] = fmaf(xk, wv.w, acc[c+3]);
    }
  }
  if (row0 + lane < n) {
    float* orow = out + (size_t)(row0 + lane) * HDIM + cbase;
#pragma unroll
    for (int c = 0; c < 48; c += 4) {
      float4 o;
      o.x = acc[c]; o.y = acc[c+1]; o.z = acc[c+2]; o.w = acc[c+3];
      *(float4*)(orow + c) = o;
    }
  }
}

extern "C" void kernel_launch(void* const* d_in, const int* in_sizes, int n_in,
                              void* d_out, int out_size, void* d_ws, size_t ws_size,
                              hipStream_t stream) {
  const float* x       = (const float*)d_in[0];
  const int*   edge    = (const int*)d_in[1];
  const float* W_local = (const float*)d_in[2];
  const float* b_local = (const float*)d_in[3];
  const float* W_g1    = (const float*)d_in[4];
  const float* b_g1    = (const float*)d_in[5];
  const float* W_g2    = (const float*)d_in[6];
  const float* b_g2    = (const float*)d_in[7];
  const float* W_fuse  = (const float*)d_in[8]; // [192, 96] row-major
  const float* b_fuse  = (const float*)d_in[9];
  float* out = (float*)d_out;

  const int n = in_sizes[0] / HDIM;
  const int e = in_sizes[1] / 2;
  const int* src = edge;
  const int* dst = edge + e;

  char* ws = (char*)d_ws;
  auto alloc = [&](size_t bytes) { char* p = ws; ws += (bytes + 255) & ~(size_t)255; return p; };
  int*   indeg   = (int*)alloc((size_t)n * 4);
  float* dis     = (float*)alloc((size_t)n * 4);
  int*   offsets = (int*)alloc((size_t)(n + 1) * 4);
  int*   rank    = (int*)alloc((size_t)e * 4);
  int*   csr_src = (int*)alloc((size_t)e * 4);
  float* bufA    = (float*)alloc((size_t)n * HDIM * 4);   // ax / ag2
  float* bufB    = (float*)alloc((size_t)n * HDIM * 4);   // local
  float* bufC    = (float*)alloc((size_t)n * HDIM * 4);   // g1 / g2

  zero_k<<<(n + 255) / 256, 256, 0, stream>>>(indeg, n);
  deg_rank_k<<<(e + 255) / 256, 256, 0, stream>>>(dst, indeg, rank, e);
  scan_dis_k<<<1, 1024, 0, stream>>>(indeg, offsets, dis, n);
  place_k<<<(e + 255) / 256, 256, 0, stream>>>(src, dst, rank, offsets, csr_src, e);

  const int ggrid = (n + 7) / 8;
  const int gb = (n + 63) / 64;

  // ax = agg(x)
  gather_k<<<ggrid, 192, 0, stream>>>(csr_src, offsets, dis, x, bufA, n);
  // local = relu(ax@W_local+b); g1 = relu(ax@W_g1+b)  (one tile read)
  gemm_row_k<true, true><<<gb, 128, 0, stream>>>(bufA, W_local, b_local, bufB,
                                                 W_g1, b_g1, bufC, n);
  // ag2 = agg(g1); g2 = relu(ag2@W_g2+b)
  gather_k<<<ggrid, 192, 0, stream>>>(csr_src, offsets, dis, bufC, bufA, n);
  gemm_row_k<true, false><<<gb, 128, 0, stream>>>(bufA, W_g2, b_g2, bufC,
                                                  nullptr, nullptr, nullptr, n);
  // out = [local | g2] @ W_fuse + b_fuse
  gemm_concat_k<<<gb, 128, 0, stream>>>(bufB, bufC, W_fuse, b_fuse, out, n);
}

// Round 5
// 414.974 us; speedup vs baseline: 1.1575x; 1.1575x over previous
//
#include <hip/hip_runtime.h>

#define HDIM 96

__global__ void zero_k(int* __restrict__ p, int n) {
  int i = blockIdx.x * blockDim.x + threadIdx.x;
  if (i < n) p[i] = 0;
}

// count in-degree AND record each edge's arrival rank at its dst
__global__ void deg_rank_k(const int* __restrict__ dst, int* __restrict__ indeg,
                           int* __restrict__ rank, int e) {
  int i = blockIdx.x * blockDim.x + threadIdx.x;
  if (i < e) rank[i] = atomicAdd(&indeg[dst[i]], 1);
}

// Single-block exclusive scan of indeg -> offsets[0..n]; also dis = rsqrt(1+indeg).
__global__ __launch_bounds__(1024) void scan_dis_k(const int* __restrict__ indeg,
                                                   int* __restrict__ offsets,
                                                   float* __restrict__ dis, int n) {
  __shared__ int wsum[16];
  __shared__ int carry_s;
  const int tid = threadIdx.x;
  const int lane = tid & 63, w = tid >> 6;
  if (tid == 0) carry_s = 0;
  __syncthreads();
  for (int base = 0; base < n; base += 1024) {
    const int i = base + tid;
    const int v = (i < n) ? indeg[i] : 0;
    int incl = v;
#pragma unroll
    for (int off = 1; off < 64; off <<= 1) {
      int t = __shfl_up(incl, off, 64);
      if (lane >= off) incl += t;
    }
    if (lane == 63) wsum[w] = incl;
    __syncthreads();
    if (tid < 16) {
      int s = wsum[tid];
#pragma unroll
      for (int off = 1; off < 16; off <<= 1) {
        int t = __shfl_up(s, off, 16);
        if (tid >= off) s += t;
      }
      wsum[tid] = s;
    }
    __syncthreads();
    const int carry = carry_s;
    incl += (w > 0 ? wsum[w - 1] : 0);
    if (i < n) {
      offsets[i] = carry + incl - v;
      dis[i] = rsqrtf((float)(1 + v));
    }
    __syncthreads();
    if (tid == 1023) carry_s = carry + incl;
    __syncthreads();
  }
  if (tid == 0) offsets[n] = carry_s;
}

// atomic-free slot calc; fire-and-forget atomicExch avoids partial-line store amplification
__global__ void place_k(const int* __restrict__ src, const int* __restrict__ dst,
                        const int* __restrict__ rank, const int* __restrict__ offsets,
                        int* __restrict__ csr_src, int e) {
  int i = blockIdx.x * blockDim.x + threadIdx.x;
  if (i >= e) return;
  int d = dst[i];
  atomicExch(&csr_src[offsets[d] + rank[i]], src[i]);
}

// agg[d,:] = dis[d] * ( dis[d]*h[d,:] + sum_{s->d} dis[s]*h[s,:] )
__global__ __launch_bounds__(192) void gather_k(
    const int* __restrict__ csr_src, const int* __restrict__ offsets,
    const float* __restrict__ dis, const float* __restrict__ h,
    float* __restrict__ agg, int n) {
  const int tid  = threadIdx.x;
  const int node = blockIdx.x * 8 + tid / 24;
  const int q    = tid % 24;
  if (node >= n) return;
  const float dd = dis[node];
  float4 acc = ((const float4*)(h + (size_t)node * HDIM))[q];
  acc.x *= dd; acc.y *= dd; acc.z *= dd; acc.w *= dd;
  int i = offsets[node];
  const int end = offsets[node + 1];
  for (; i + 1 < end; i += 2) {
    const int s0 = csr_src[i], s1 = csr_src[i + 1];
    const float w0 = dis[s0], w1 = dis[s1];
    const float4 v0 = ((const float4*)(h + (size_t)s0 * HDIM))[q];
    const float4 v1 = ((const float4*)(h + (size_t)s1 * HDIM))[q];
    acc.x = fmaf(w0, v0.x, acc.x); acc.y = fmaf(w0, v0.y, acc.y);
    acc.z = fmaf(w0, v0.z, acc.z); acc.w = fmaf(w0, v0.w, acc.w);
    acc.x = fmaf(w1, v1.x, acc.x); acc.y = fmaf(w1, v1.y, acc.y);
    acc.z = fmaf(w1, v1.z, acc.z); acc.w = fmaf(w1, v1.w, acc.w);
  }
  if (i < end) {
    const int s0 = csr_src[i];
    const float w0 = dis[s0];
    const float4 v0 = ((const float4*)(h + (size_t)s0 * HDIM))[q];
    acc.x = fmaf(w0, v0.x, acc.x); acc.y = fmaf(w0, v0.y, acc.y);
    acc.z = fmaf(w0, v0.z, acc.z); acc.w = fmaf(w0, v0.w, acc.w);
  }
  acc.x *= dd; acc.y *= dd; acc.z *= dd; acc.w *= dd;
  ((float4*)(agg + (size_t)node * HDIM))[q] = acc;
}

// ---- 2D register-blocked fp32 GEMM ----
// out[n,96] = [A0 | A1][n, 32*nkt] @ W[32*nkt, 96] + bias  (A1 used for kt>=3)
// Block: 192 threads = 16 rowg x 12 colg; tile 128 rows x 96 cols; 8x8 per thread.
// K tiled by 32: AsT (transposed, stride 132) 16.9KB + Ws 12.3KB = 29.2KB -> 5 blocks/CU.
template<bool RELU>
__global__ __launch_bounds__(192, 4) void gemm_tile_k(
    const float* __restrict__ A0, const float* __restrict__ A1,
    const float* __restrict__ W, const float* __restrict__ bias,
    float* __restrict__ out, int n, int nkt) {
  __shared__ float AsT[32 * 132];
  __shared__ float Ws[32 * 96];
  const int t  = threadIdx.x;
  const int cg = t % 12;          // col group: cols [8cg, 8cg+8)
  const int rg = t / 12;          // row group: rows [8rg, 8rg+8)
  const int row0 = blockIdx.x * 128;

  float acc[8][8];
  {
    const float4 b0 = *(const float4*)(bias + cg * 8);
    const float4 b1 = *(const float4*)(bias + cg * 8 + 4);
#pragma unroll
    for (int j = 0; j < 8; j++) {
      acc[j][0] = b0.x; acc[j][1] = b0.y; acc[j][2] = b0.z; acc[j][3] = b0.w;
      acc[j][4] = b1.x; acc[j][5] = b1.y; acc[j][6] = b1.z; acc[j][7] = b1.w;
    }
  }

  for (int kt = 0; kt < nkt; kt++) {
    const float* A = (kt < 3) ? A0 : A1;
    const int kA = (kt < 3 ? kt : kt - 3) * 32;   // k-offset within the A matrix
    const int kW = kt * 32;                       // k-offset within W (concat: 0..191)
    __syncthreads();
    // stage A tile (128 rows x 32 k), transposed into AsT[k][r]
    for (int idx = t; idx < 1024; idx += 192) {
      const int r = idx >> 3, q = idx & 7;
      float4 v = make_float4(0.f, 0.f, 0.f, 0.f);
      if (row0 + r < n) v = *(const float4*)(A + (size_t)(row0 + r) * HDIM + kA + 4 * q);
      AsT[(4 * q + 0) * 132 + r] = v.x;
      AsT[(4 * q + 1) * 132 + r] = v.y;
      AsT[(4 * q + 2) * 132 + r] = v.z;
      AsT[(4 * q + 3) * 132 + r] = v.w;
    }
    // stage W tile (32 k-rows x 96 cols) — contiguous flat copy
    for (int idx = t; idx < 768; idx += 192) {
      ((float4*)Ws)[idx] = *(const float4*)(W + (size_t)kW * HDIM + 4 * idx);
    }
    __syncthreads();
#pragma unroll 2
    for (int k = 0; k < 32; k++) {
      const float4 a0 = *(const float4*)(&AsT[k * 132 + rg * 8]);
      const float4 a1 = *(const float4*)(&AsT[k * 132 + rg * 8 + 4]);
      const float4 w0 = *(const float4*)(&Ws[k * HDIM + cg * 8]);
      const float4 w1 = *(const float4*)(&Ws[k * HDIM + cg * 8 + 4]);
      const float av[8] = {a0.x, a0.y, a0.z, a0.w, a1.x, a1.y, a1.z, a1.w};
      const float wv[8] = {w0.x, w0.y, w0.z, w0.w, w1.x, w1.y, w1.z, w1.w};
#pragma unroll
      for (int j = 0; j < 8; j++)
#pragma unroll
        for (int c = 0; c < 8; c++)
          acc[j][c] = fmaf(av[j], wv[c], acc[j][c]);
    }
  }

#pragma unroll
  for (int j = 0; j < 8; j++) {
    const int r = row0 + rg * 8 + j;
    if (r < n) {
      float o[8];
#pragma unroll
      for (int c = 0; c < 8; c++) o[c] = RELU ? fmaxf(acc[j][c], 0.f) : acc[j][c];
      float* orow = out + (size_t)r * HDIM + cg * 8;
      *(float4*)(orow)     = make_float4(o[0], o[1], o[2], o[3]);
      *(float4*)(orow + 4) = make_float4(o[4], o[5], o[6], o[7]);
    }
  }
}

extern "C" void kernel_launch(void* const* d_in, const int* in_sizes, int n_in,
                              void* d_out, int out_size, void* d_ws, size_t ws_size,
                              hipStream_t stream) {
  const float* x       = (const float*)d_in[0];
  const int*   edge    = (const int*)d_in[1];
  const float* W_local = (const float*)d_in[2];
  const float* b_local = (const float*)d_in[3];
  const float* W_g1    = (const float*)d_in[4];
  const float* b_g1    = (const float*)d_in[5];
  const float* W_g2    = (const float*)d_in[6];
  const float* b_g2    = (const float*)d_in[7];
  const float* W_fuse  = (const float*)d_in[8]; // [192, 96] row-major
  const float* b_fuse  = (const float*)d_in[9];
  float* out = (float*)d_out;

  const int n = in_sizes[0] / HDIM;
  const int e = in_sizes[1] / 2;
  const int* src = edge;
  const int* dst = edge + e;

  char* ws = (char*)d_ws;
  auto alloc = [&](size_t bytes) { char* p = ws; ws += (bytes + 255) & ~(size_t)255; return p; };
  int*   indeg   = (int*)alloc((size_t)n * 4);
  float* dis     = (float*)alloc((size_t)n * 4);
  int*   offsets = (int*)alloc((size_t)(n + 1) * 4);
  int*   rank    = (int*)alloc((size_t)e * 4);
  int*   csr_src = (int*)alloc((size_t)e * 4);
  float* bufA    = (float*)alloc((size_t)n * HDIM * 4);   // ax / ag2
  float* bufB    = (float*)alloc((size_t)n * HDIM * 4);   // local
  float* bufC    = (float*)alloc((size_t)n * HDIM * 4);   // g1 / g2

  zero_k<<<(n + 255) / 256, 256, 0, stream>>>(indeg, n);
  deg_rank_k<<<(e + 255) / 256, 256, 0, stream>>>(dst, indeg, rank, e);
  scan_dis_k<<<1, 1024, 0, stream>>>(indeg, offsets, dis, n);
  place_k<<<(e + 255) / 256, 256, 0, stream>>>(src, dst, rank, offsets, csr_src, e);

  const int ggrid = (n + 7) / 8;
  const int gb = (n + 127) / 128;

  // ax = agg(x)
  gather_k<<<ggrid, 192, 0, stream>>>(csr_src, offsets, dis, x, bufA, n);
  // local = relu(ax@W_local+b); g1 = relu(ax@W_g1+b)
  gemm_tile_k<true><<<gb, 192, 0, stream>>>(bufA, nullptr, W_local, b_local, bufB, n, 3);
  gemm_tile_k<true><<<gb, 192, 0, stream>>>(bufA, nullptr, W_g1, b_g1, bufC, n, 3);
  // ag2 = agg(g1); g2 = relu(ag2@W_g2+b)
  gather_k<<<ggrid, 192, 0, stream>>>(csr_src, offsets, dis, bufC, bufA, n);
  gemm_tile_k<true><<<gb, 192, 0, stream>>>(bufA, nullptr, W_g2, b_g2, bufC, n, 3);
  // out = [local | g2] @ W_fuse + b_fuse   (K=192)
  gemm_tile_k<false><<<gb, 192, 0, stream>>>(bufB, bufC, W_fuse, b_fuse, out, n, 6);
}

// Round 6
// 376.516 us; speedup vs baseline: 1.2757x; 1.1021x over previous
//
#include <hip/hip_runtime.h>

#define HDIM 96

__global__ void zero_k(int* __restrict__ p, int n) {
  int i = blockIdx.x * blockDim.x + threadIdx.x;
  if (i < n) p[i] = 0;
}

// count in-degree AND record each edge's arrival rank at its dst
__global__ void deg_rank_k(const int* __restrict__ dst, int* __restrict__ indeg,
                           int* __restrict__ rank, int e) {
  int i = blockIdx.x * blockDim.x + threadIdx.x;
  if (i < e) rank[i] = atomicAdd(&indeg[dst[i]], 1);
}

__device__ __forceinline__ int wave_incl_scan(int v, int lane) {
#pragma unroll
  for (int off = 1; off < 64; off <<= 1) {
    int t = __shfl_up(v, off, 64);
    if (lane >= off) v += t;
  }
  return v;
}

// Phase A: bsum[b] = sum of indeg[b*1024 .. b*1024+1024)
__global__ __launch_bounds__(1024) void scan_a_k(const int* __restrict__ indeg,
                                                 int* __restrict__ bsum, int n) {
  const int tid = threadIdx.x;
  const int i = blockIdx.x * 1024 + tid;
  int v = (i < n) ? indeg[i] : 0;
#pragma unroll
  for (int off = 32; off; off >>= 1) v += __shfl_down(v, off, 64);
  __shared__ int ws[16];
  if ((tid & 63) == 0) ws[tid >> 6] = v;
  __syncthreads();
  if (tid < 16) {
    int s = ws[tid];
#pragma unroll
    for (int off = 8; off; off >>= 1) s += __shfl_down(s, off, 16);
    if (tid == 0) bsum[blockIdx.x] = s;
  }
}

// Phase B: exclusive scan of bsum[0..nb) -> bbase; offsets[n] = grand total. nb <= 1024.
__global__ __launch_bounds__(1024) void scan_b_k(const int* __restrict__ bsum,
                                                 int* __restrict__ bbase,
                                                 int* __restrict__ offsets, int nb, int n) {
  __shared__ int ws[16];
  const int tid = threadIdx.x, lane = tid & 63, w = tid >> 6;
  const int v = (tid < nb) ? bsum[tid] : 0;
  int incl = wave_incl_scan(v, lane);
  if (lane == 63) ws[w] = incl;
  __syncthreads();
  if (tid < 16) {
    int s = ws[tid];
#pragma unroll
    for (int off = 1; off < 16; off <<= 1) {
      int t = __shfl_up(s, off, 16);
      if (tid >= off) s += t;
    }
    ws[tid] = s;
  }
  __syncthreads();
  incl += (w > 0 ? ws[w - 1] : 0);
  if (tid < nb) bbase[tid] = incl - v;
  if (tid == 0) offsets[n] = ws[15];
}

// Phase C: per-chunk rescan + base add; also dis = rsqrt(1+indeg)
__global__ __launch_bounds__(1024) void scan_c_k(const int* __restrict__ indeg,
                                                 const int* __restrict__ bbase,
                                                 int* __restrict__ offsets,
                                                 float* __restrict__ dis, int n) {
  __shared__ int ws[16];
  const int tid = threadIdx.x, lane = tid & 63, w = tid >> 6;
  const int i = blockIdx.x * 1024 + tid;
  const int v = (i < n) ? indeg[i] : 0;
  int incl = wave_incl_scan(v, lane);
  if (lane == 63) ws[w] = incl;
  __syncthreads();
  if (tid < 16) {
    int s = ws[tid];
#pragma unroll
    for (int off = 1; off < 16; off <<= 1) {
      int t = __shfl_up(s, off, 16);
      if (tid >= off) s += t;
    }
    ws[tid] = s;
  }
  __syncthreads();
  incl += (w > 0 ? ws[w - 1] : 0);
  if (i < n) {
    offsets[i] = bbase[blockIdx.x] + incl - v;
    dis[i] = rsqrtf((float)(1 + v));
  }
}

// atomic-free slot calc; fire-and-forget atomicExch avoids partial-line store amplification
__global__ void place_k(const int* __restrict__ src, const int* __restrict__ dst,
                        const int* __restrict__ rank, const int* __restrict__ offsets,
                        int* __restrict__ csr_src, int e) {
  int i = blockIdx.x * blockDim.x + threadIdx.x;
  if (i >= e) return;
  int d = dst[i];
  atomicExch(&csr_src[offsets[d] + rank[i]], src[i]);
}

// o[i,:] = dis[i] * x[i,:]
__global__ void scale_k(const float* __restrict__ x, const float* __restrict__ dis,
                        float* __restrict__ o, int n) {
  int t = blockIdx.x * blockDim.x + threadIdx.x;
  if (t >= n * 24) return;
  const float d = dis[t / 24];
  float4 v = ((const float4*)x)[t];
  v.x *= d; v.y *= d; v.z *= d; v.w *= d;
  ((float4*)o)[t] = v;
}

// agg[d,:] = dis[d] * ( hp[d,:] + sum_{s->d} hp[s,:] )   (hp is pre-scaled dis*h)
__global__ __launch_bounds__(192) void gather_k(
    const int* __restrict__ csr_src, const int* __restrict__ offsets,
    const float* __restrict__ dis, const float* __restrict__ hp,
    float* __restrict__ agg, int n) {
  const int tid  = threadIdx.x;
  const int node = blockIdx.x * 8 + tid / 24;
  const int q    = tid % 24;
  if (node >= n) return;
  float4 acc = ((const float4*)(hp + (size_t)node * HDIM))[q];   // self term
  int i = offsets[node];
  const int end = offsets[node + 1];
  for (; i + 3 < end; i += 4) {
    const int s0 = csr_src[i], s1 = csr_src[i + 1], s2 = csr_src[i + 2], s3 = csr_src[i + 3];
    const float4 v0 = ((const float4*)(hp + (size_t)s0 * HDIM))[q];
    const float4 v1 = ((const float4*)(hp + (size_t)s1 * HDIM))[q];
    const float4 v2 = ((const float4*)(hp + (size_t)s2 * HDIM))[q];
    const float4 v3 = ((const float4*)(hp + (size_t)s3 * HDIM))[q];
    acc.x += v0.x + v1.x + v2.x + v3.x;
    acc.y += v0.y + v1.y + v2.y + v3.y;
    acc.z += v0.z + v1.z + v2.z + v3.z;
    acc.w += v0.w + v1.w + v2.w + v3.w;
  }
  for (; i < end; i++) {
    const int s0 = csr_src[i];
    const float4 v0 = ((const float4*)(hp + (size_t)s0 * HDIM))[q];
    acc.x += v0.x; acc.y += v0.y; acc.z += v0.z; acc.w += v0.w;
  }
  const float dd = dis[node];
  acc.x *= dd; acc.y *= dd; acc.z *= dd; acc.w *= dd;
  ((float4*)(agg + (size_t)node * HDIM))[q] = acc;
}

// ---- 2D register-blocked fp32 GEMM ----
// out[n,96] = [A0 | A1][n, 32*nkt] @ W[32*nkt, 96] + bias  (A1 used for kt>=3)
// Block: 192 threads = 16 rowg x 12 colg; tile 128 rows x 96 cols; 8x8 per thread.
// K tiled by 32: AsT (transposed, stride 132) 16.9KB + Ws 12.3KB = 29.2KB -> 5 blocks/CU.
// SCALE: multiply output row by dis[row] (fused message pre-scaling for the next hop).
template<bool RELU, bool SCALE>
__global__ __launch_bounds__(192, 4) void gemm_tile_k(
    const float* __restrict__ A0, const float* __restrict__ A1,
    const float* __restrict__ W, const float* __restrict__ bias,
    const float* __restrict__ dis, float* __restrict__ out, int n, int nkt) {
  __shared__ float AsT[32 * 132];
  __shared__ float Ws[32 * 96];
  const int t  = threadIdx.x;
  const int cg = t % 12;          // col group: cols [8cg, 8cg+8)
  const int rg = t / 12;          // row group: rows [8rg, 8rg+8)
  const int row0 = blockIdx.x * 128;

  float acc[8][8];
  {
    const float4 b0 = *(const float4*)(bias + cg * 8);
    const float4 b1 = *(const float4*)(bias + cg * 8 + 4);
#pragma unroll
    for (int j = 0; j < 8; j++) {
      acc[j][0] = b0.x; acc[j][1] = b0.y; acc[j][2] = b0.z; acc[j][3] = b0.w;
      acc[j][4] = b1.x; acc[j][5] = b1.y; acc[j][6] = b1.z; acc[j][7] = b1.w;
    }
  }

  for (int kt = 0; kt < nkt; kt++) {
    const float* A = (kt < 3) ? A0 : A1;
    const int kA = (kt < 3 ? kt : kt - 3) * 32;   // k-offset within the A matrix
    const int kW = kt * 32;                       // k-offset within W (concat: 0..191)
    __syncthreads();
    // stage A tile (128 rows x 32 k), transposed into AsT[k][r]
    for (int idx = t; idx < 1024; idx += 192) {
      const int r = idx >> 3, q = idx & 7;
      float4 v = make_float4(0.f, 0.f, 0.f, 0.f);
      if (row0 + r < n) v = *(const float4*)(A + (size_t)(row0 + r) * HDIM + kA + 4 * q);
      AsT[(4 * q + 0) * 132 + r] = v.x;
      AsT[(4 * q + 1) * 132 + r] = v.y;
      AsT[(4 * q + 2) * 132 + r] = v.z;
      AsT[(4 * q + 3) * 132 + r] = v.w;
    }
    // stage W tile (32 k-rows x 96 cols) — contiguous flat copy
    for (int idx = t; idx < 768; idx += 192) {
      ((float4*)Ws)[idx] = *(const float4*)(W + (size_t)kW * HDIM + 4 * idx);
    }
    __syncthreads();
#pragma unroll 2
    for (int k = 0; k < 32; k++) {
      const float4 a0 = *(const float4*)(&AsT[k * 132 + rg * 8]);
      const float4 a1 = *(const float4*)(&AsT[k * 132 + rg * 8 + 4]);
      const float4 w0 = *(const float4*)(&Ws[k * HDIM + cg * 8]);
      const float4 w1 = *(const float4*)(&Ws[k * HDIM + cg * 8 + 4]);
      const float av[8] = {a0.x, a0.y, a0.z, a0.w, a1.x, a1.y, a1.z, a1.w};
      const float wv[8] = {w0.x, w0.y, w0.z, w0.w, w1.x, w1.y, w1.z, w1.w};
#pragma unroll
      for (int j = 0; j < 8; j++)
#pragma unroll
        for (int c = 0; c < 8; c++)
          acc[j][c] = fmaf(av[j], wv[c], acc[j][c]);
    }
  }

#pragma unroll
  for (int j = 0; j < 8; j++) {
    const int r = row0 + rg * 8 + j;
    if (r < n) {
      float o[8];
#pragma unroll
      for (int c = 0; c < 8; c++) o[c] = RELU ? fmaxf(acc[j][c], 0.f) : acc[j][c];
      if (SCALE) {
        const float d = dis[r];
#pragma unroll
        for (int c = 0; c < 8; c++) o[c] *= d;
      }
      float* orow = out + (size_t)r * HDIM + cg * 8;
      *(float4*)(orow)     = make_float4(o[0], o[1], o[2], o[3]);
      *(float4*)(orow + 4) = make_float4(o[4], o[5], o[6], o[7]);
    }
  }
}

extern "C" void kernel_launch(void* const* d_in, const int* in_sizes, int n_in,
                              void* d_out, int out_size, void* d_ws, size_t ws_size,
                              hipStream_t stream) {
  const float* x       = (const float*)d_in[0];
  const int*   edge    = (const int*)d_in[1];
  const float* W_local = (const float*)d_in[2];
  const float* b_local = (const float*)d_in[3];
  const float* W_g1    = (const float*)d_in[4];
  const float* b_g1    = (const float*)d_in[5];
  const float* W_g2    = (const float*)d_in[6];
  const float* b_g2    = (const float*)d_in[7];
  const float* W_fuse  = (const float*)d_in[8]; // [192, 96] row-major
  const float* b_fuse  = (const float*)d_in[9];
  float* out = (float*)d_out;

  const int n = in_sizes[0] / HDIM;
  const int e = in_sizes[1] / 2;
  const int* src = edge;
  const int* dst = edge + e;
  const int nb = (n + 1023) / 1024;

  char* ws = (char*)d_ws;
  auto alloc = [&](size_t bytes) { char* p = ws; ws += (bytes + 255) & ~(size_t)255; return p; };
  int*   indeg   = (int*)alloc((size_t)n * 4);
  float* dis     = (float*)alloc((size_t)n * 4);
  int*   offsets = (int*)alloc((size_t)(n + 1) * 4);
  int*   bsum    = (int*)alloc((size_t)nb * 4);
  int*   bbase   = (int*)alloc((size_t)nb * 4);
  int*   rank    = (int*)alloc((size_t)e * 4);
  int*   csr_src = (int*)alloc((size_t)e * 4);
  float* bufA    = (float*)alloc((size_t)n * HDIM * 4);   // ax / ag2
  float* bufB    = (float*)alloc((size_t)n * HDIM * 4);   // x' then local
  float* bufC    = (float*)alloc((size_t)n * HDIM * 4);   // g1' then g2

  zero_k<<<(n + 255) / 256, 256, 0, stream>>>(indeg, n);
  deg_rank_k<<<(e + 255) / 256, 256, 0, stream>>>(dst, indeg, rank, e);
  scan_a_k<<<nb, 1024, 0, stream>>>(indeg, bsum, n);
  scan_b_k<<<1, 1024, 0, stream>>>(bsum, bbase, offsets, nb, n);
  scan_c_k<<<nb, 1024, 0, stream>>>(indeg, bbase, offsets, dis, n);
  place_k<<<(e + 255) / 256, 256, 0, stream>>>(src, dst, rank, offsets, csr_src, e);

  const int ggrid = (n + 7) / 8;
  const int gb = (n + 127) / 128;

  // x' = dis·x  (bufB is free until the local GEMM overwrites it)
  scale_k<<<(n * 24 + 255) / 256, 256, 0, stream>>>(x, dis, bufB, n);
  // ax = dis·(x'[d] + Σ x'[s])
  gather_k<<<ggrid, 192, 0, stream>>>(csr_src, offsets, dis, bufB, bufA, n);
  // local = relu(ax@W_local+b);  g1' = dis·relu(ax@W_g1+b)
  gemm_tile_k<true, false><<<gb, 192, 0, stream>>>(bufA, nullptr, W_local, b_local, nullptr, bufB, n, 3);
  gemm_tile_k<true, true><<<gb, 192, 0, stream>>>(bufA, nullptr, W_g1, b_g1, dis, bufC, n, 3);
  // ag2 = dis·(g1'[d] + Σ g1'[s]);  g2 = relu(ag2@W_g2+b)
  gather_k<<<ggrid, 192, 0, stream>>>(csr_src, offsets, dis, bufC, bufA, n);
  gemm_tile_k<true, false><<<gb, 192, 0, stream>>>(bufA, nullptr, W_g2, b_g2, nullptr, bufC, n, 3);
  // out = [local | g2] @ W_fuse + b_fuse   (K=192)
  gemm_tile_k<false, false><<<gb, 192, 0, stream>>>(bufB, bufC, W_fuse, b_fuse, nullptr, out, n, 6);
}